// Round 6
// baseline (1210.176 us; speedup 1.0000x reference)
//
#include <hip/hip_runtime.h>
#include <hip/hip_bf16.h>

#define F 128

typedef unsigned int uint;
typedef unsigned short ushort;
typedef __attribute__((ext_vector_type(8))) short short8;   // 8 bf16
typedef __attribute__((ext_vector_type(4))) float f32x4;

__device__ inline ushort f2bf(float f) {
    uint u = __float_as_uint(f);
    u += 0x7FFF + ((u >> 16) & 1);   // round-to-nearest-even
    return (ushort)(u >> 16);
}
__device__ inline float2 bf2f(uint u) {
    return make_float2(__uint_as_float(u << 16), __uint_as_float(u & 0xFFFF0000u));
}

// ---------------- CSR build ----------------
__global__ __launch_bounds__(256) void hist_kernel(const int* __restrict__ dst,
                                                   int* __restrict__ cnt, int E) {
    int e = blockIdx.x * 256 + threadIdx.x;
    if (e < E) atomicAdd(&cnt[dst[e]], 1);
}

__global__ __launch_bounds__(256) void scan_block(const int* __restrict__ cnt,
                                                  int* __restrict__ off,
                                                  int* __restrict__ bsum, int N) {
    __shared__ int t[256];
    int i = blockIdx.x * 256 + threadIdx.x;
    int v = (i < N) ? cnt[i] : 0;
    t[threadIdx.x] = v;
    __syncthreads();
    for (int o = 1; o < 256; o <<= 1) {
        int x = (threadIdx.x >= o) ? t[threadIdx.x - o] : 0;
        __syncthreads();
        t[threadIdx.x] += x;
        __syncthreads();
    }
    if (i < N) off[i] = t[threadIdx.x] - v;
    if (threadIdx.x == 255) bsum[blockIdx.x] = t[255];
}

__global__ __launch_bounds__(512) void scan_sums(int* __restrict__ bsum, int nb) {
    __shared__ int t[512];
    int v = (threadIdx.x < nb) ? bsum[threadIdx.x] : 0;
    t[threadIdx.x] = v;
    __syncthreads();
    for (int o = 1; o < 512; o <<= 1) {
        int x = (threadIdx.x >= o) ? t[threadIdx.x - o] : 0;
        __syncthreads();
        t[threadIdx.x] += x;
        __syncthreads();
    }
    if (threadIdx.x < nb) bsum[threadIdx.x] = t[threadIdx.x] - v;
}

__global__ __launch_bounds__(256) void scan_add(int* __restrict__ off,
                                                const int* __restrict__ bsum, int N) {
    int i = blockIdx.x * 256 + threadIdx.x;
    if (i < N) off[i] += bsum[blockIdx.x];
}

__global__ __launch_bounds__(256) void rdeg_cur(const int* __restrict__ off,
                                                float* __restrict__ rdeg,
                                                int* __restrict__ cur, int N, int E) {
    int i = blockIdx.x * 256 + threadIdx.x;
    if (i >= N) return;
    int b = off[i];
    int e = (i == N - 1) ? E : off[i + 1];
    rdeg[i] = 1.0f / fmaxf((float)(e - b), 1.0f);
    cur[i] = b;
}

__global__ __launch_bounds__(256) void scatter_kernel(const int* __restrict__ src,
                                                      const int* __restrict__ dst,
                                                      int* __restrict__ cur,
                                                      int2* __restrict__ sE, int E) {
    int e = blockIdx.x * 256 + threadIdx.x;
    if (e >= E) return;
    int d = dst[e];
    int p = atomicAdd(&cur[d], 1);
    sE[p] = make_int2(src[e], e);
}

// ---------------- weight prep: cast + transpose 4 matrices [k][n] -> bf16 [n][k] ----------------
__global__ __launch_bounds__(256) void wprep(const float* __restrict__ W0,
                                             const float* __restrict__ W1,
                                             const float* __restrict__ W2,
                                             const float* __restrict__ W3,
                                             ushort* __restrict__ Wt) {
    int idx = blockIdx.x * 256 + threadIdx.x;   // 4 * 128*128
    if (idx >= 4 * 16384) return;
    int mat = idx >> 14;
    int pos = idx & 16383;
    int k = pos >> 7, n = pos & 127;
    const float* W = (mat == 0) ? W0 : (mat == 1) ? W1 : (mat == 2) ? W2 : W3;
    Wt[mat * 16384 + n * 128 + k] = f2bf(W[k * 128 + n]);
}

// ---------------- f32 -> bf16 cast (x only) ----------------
__global__ __launch_bounds__(256) void cast_bf16(const float* __restrict__ in,
                                                 uint* __restrict__ outb, int n4) {
    int i = blockIdx.x * 256 + threadIdx.x;
    if (i >= n4) return;
    float4 v = ((const float4*)in)[i];
    uint ua = (uint)f2bf(v.x) | ((uint)f2bf(v.y) << 16);
    uint ub = (uint)f2bf(v.z) | ((uint)f2bf(v.w) << 16);
    ((uint2*)outb)[i] = make_uint2(ua, ub);
}

// ---------------- aggregate (gather, R4-proven shape): msg[n] = mean h[srcs] ----------------
// wave per node, lane per bf16x2; p wave-uniform -> scalar CSR loads, coalesced row loads.
__global__ __launch_bounds__(256) void agg_gather(const uint* __restrict__ hb,
                                                  const int* __restrict__ off,
                                                  const int2* __restrict__ sE,
                                                  const float* __restrict__ rdeg,
                                                  uint* __restrict__ msgb, int N, int E) {
    int node = blockIdx.x * 4 + (threadIdx.x >> 6);
    int lane = threadIdx.x & 63;
    if (node >= N) return;
    int p = off[node];
    int pe = (node == N - 1) ? E : off[node + 1];
    float2 acc = make_float2(0.f, 0.f);
    for (; p + 3 < pe; p += 4) {
        int s0 = sE[p].x, s1 = sE[p + 1].x, s2 = sE[p + 2].x, s3 = sE[p + 3].x;
        float2 f0 = bf2f(hb[(size_t)s0 * 64 + lane]);
        float2 f1 = bf2f(hb[(size_t)s1 * 64 + lane]);
        float2 f2 = bf2f(hb[(size_t)s2 * 64 + lane]);
        float2 f3 = bf2f(hb[(size_t)s3 * 64 + lane]);
        acc.x += (f0.x + f1.x) + (f2.x + f3.x);
        acc.y += (f0.y + f1.y) + (f2.y + f3.y);
    }
    for (; p < pe; ++p) {
        float2 f = bf2f(hb[(size_t)sE[p].x * 64 + lane]);
        acc.x += f.x;
        acc.y += f.y;
    }
    float rd = rdeg[node];
    msgb[(size_t)node * 64 + lane] = (uint)f2bf(acc.x * rd) | ((uint)f2bf(acc.y * rd) << 16);
}

// ---------------- SAGE layer via MFMA ----------------
__global__ __launch_bounds__(256) void sage_mfma(const uint* __restrict__ hb,
                                                 const uint* __restrict__ mb,
                                                 const uint* __restrict__ Wt,
                                                 const float* __restrict__ bias,
                                                 ushort* __restrict__ outb, int N) {
    int wave = threadIdx.x >> 6, lane = threadIdx.x & 63;
    int m = lane & 15, q = lane >> 4;
    int r0 = blockIdx.x * 64 + wave * 16;
    int arow = r0 + m;
    if (arow >= N) arow = N - 1;

    f32x4 acc[8];
#pragma unroll
    for (int t = 0; t < 8; t++) acc[t] = (f32x4){0.f, 0.f, 0.f, 0.f};

    const uint* hrow = hb + (size_t)arow * 64;
    const uint* mrow = mb + (size_t)arow * 64;
#pragma unroll
    for (int sel = 0; sel < 2; sel++) {
        const uint* arowp = sel ? mrow : hrow;
        const uint* wsel = Wt + sel * 8192;
#pragma unroll
        for (int kk = 0; kk < 4; kk++) {
            int ko = kk * 16 + q * 4;
            short8 a = *(const short8*)(arowp + ko);
#pragma unroll
            for (int t = 0; t < 8; t++) {
                short8 b = *(const short8*)(wsel + (size_t)(16 * t + m) * 64 + ko);
                acc[t] = __builtin_amdgcn_mfma_f32_16x16x32_bf16(a, b, acc[t], 0, 0, 0);
            }
        }
    }

#pragma unroll
    for (int t = 0; t < 8; t++) {
        float bs = bias[16 * t + m];
#pragma unroll
        for (int r = 0; r < 4; r++) {
            int orow = r0 + q * 4 + r;
            if (orow < N) outb[(size_t)orow * 128 + 16 * t + m] = f2bf(acc[t][r] + bs);
        }
    }
}

// ---------------- min/max encode ----------------
__device__ inline unsigned enc_f(float f) {
    unsigned u = __float_as_uint(f);
    return (u & 0x80000000u) ? ~u : (u | 0x80000000u);
}
__device__ inline float dec_f(unsigned u) {
    return (u & 0x80000000u) ? __uint_as_float(u & 0x7FFFFFFFu) : __uint_as_float(~u);
}

// ---------------- edge score (R4-proven shape + 4-edge unroll, fused min/max) ----------------
__global__ __launch_bounds__(256) void edge_score_csr(const uint* __restrict__ hb,
                                                      const int* __restrict__ off,
                                                      const int2* __restrict__ sE,
                                                      float* __restrict__ s,
                                                      unsigned* __restrict__ mm, int N, int E) {
    int node = blockIdx.x * 4 + (threadIdx.x >> 6);
    int lane = threadIdx.x & 63;
    float lmin = INFINITY, lmax = -INFINITY;

    if (node < N) {
        int p = off[node];
        int pe = (node == N - 1) ? E : off[node + 1];
        if (p < pe) {
            float2 d = bf2f(hb[(size_t)node * 64 + lane]);
            for (; p + 3 < pe; p += 4) {
                int2 se0 = sE[p], se1 = sE[p + 1], se2 = sE[p + 2], se3 = sE[p + 3];
                float2 a0 = bf2f(hb[(size_t)se0.x * 64 + lane]);
                float2 a1 = bf2f(hb[(size_t)se1.x * 64 + lane]);
                float2 a2 = bf2f(hb[(size_t)se2.x * 64 + lane]);
                float2 a3 = bf2f(hb[(size_t)se3.x * 64 + lane]);
                float v0 = a0.x * d.x + a0.y * d.y;
                float v1 = a1.x * d.x + a1.y * d.y;
                float v2 = a2.x * d.x + a2.y * d.y;
                float v3 = a3.x * d.x + a3.y * d.y;
#pragma unroll
                for (int o = 32; o > 0; o >>= 1) {
                    v0 += __shfl_down(v0, o);
                    v1 += __shfl_down(v1, o);
                    v2 += __shfl_down(v2, o);
                    v3 += __shfl_down(v3, o);
                }
                if (lane == 0) {
                    s[se0.y] = v0; s[se1.y] = v1; s[se2.y] = v2; s[se3.y] = v3;
                    float mn = fminf(fminf(v0, v1), fminf(v2, v3));
                    float mx = fmaxf(fmaxf(v0, v1), fmaxf(v2, v3));
                    lmin = fminf(lmin, mn);
                    lmax = fmaxf(lmax, mx);
                }
            }
            for (; p < pe; ++p) {
                int2 se = sE[p];
                float2 a = bf2f(hb[(size_t)se.x * 64 + lane]);
                float v = a.x * d.x + a.y * d.y;
#pragma unroll
                for (int o = 32; o > 0; o >>= 1) v += __shfl_down(v, o);
                if (lane == 0) {
                    s[se.y] = v;
                    lmin = fminf(lmin, v);
                    lmax = fmaxf(lmax, v);
                }
            }
        }
    }

    // non-lane-0 lanes hold +/-INF -> harmless in the reduction
#pragma unroll
    for (int o = 1; o <= 32; o <<= 1) {
        lmin = fminf(lmin, __shfl_xor(lmin, o));
        lmax = fmaxf(lmax, __shfl_xor(lmax, o));
    }
    __shared__ float smin[4], smax[4];
    int wv = threadIdx.x >> 6;
    if (lane == 0) { smin[wv] = lmin; smax[wv] = lmax; }
    __syncthreads();
    if (threadIdx.x == 0) {
        float m = fminf(fminf(smin[0], smin[1]), fminf(smin[2], smin[3]));
        float M = fmaxf(fmaxf(smax[0], smax[1]), fmaxf(smax[2], smax[3]));
        atomicMin(&mm[0], enc_f(m));
        atomicMax(&mm[1], enc_f(M));
    }
}

__global__ __launch_bounds__(256) void norm_kernel(float* __restrict__ s,
                                                   const unsigned* __restrict__ mm, int E) {
    float mn = dec_f(mm[0]);
    float mx = dec_f(mm[1]);
    float inv = 1.0f / (mx - mn);
    int i = blockIdx.x * 256 + threadIdx.x;
    if (i < E) s[i] = (s[i] - mn) * inv;
}

extern "C" void kernel_launch(void* const* d_in, const int* in_sizes, int n_in,
                              void* d_out, int out_size, void* d_ws, size_t ws_size,
                              hipStream_t stream) {
    const float* x   = (const float*)d_in[0];
    const int*   src = (const int*)d_in[1];
    const int*   dst = (const int*)d_in[2];
    const float* Ws1 = (const float*)d_in[3];
    const float* Wn1 = (const float*)d_in[4];
    const float* b1  = (const float*)d_in[5];
    const float* Ws2 = (const float*)d_in[6];
    const float* Wn2 = (const float*)d_in[7];
    const float* b2  = (const float*)d_in[8];

    int N = in_sizes[0] / F;   // 100000
    int E = in_sizes[1];       // 1600000
    float* out = (float*)d_out;

    // workspace layout (4-byte elements)
    int* off  = (int*)d_ws;                  // N
    int* cur  = off + N;                     // N
    int2* sE  = (int2*)(cur + N);            // E int2 (2E words)
    int* bsum = (int*)(sE + E);              // 1024
    float* rdeg = (float*)(bsum + 1024);     // N
    unsigned* mm = (unsigned*)(rdeg + N);    // 4 (2 used)
    uint* Wtb = (uint*)(mm + 4);             // 4*16384 bf16 = 32768 uints
    size_t elemOff = 3 * (size_t)N + 2 * (size_t)E + 1024 + 4 + 32768;
    elemOff = (elemOff + 3) & ~(size_t)3;    // 16B align
    uint* xb   = (uint*)d_ws + elemOff;      // N*64
    uint* msgb = xb + (size_t)N * 64;        // N*64
    uint* h1b  = msgb + (size_t)N * 64;      // N*64
    uint* h2b  = h1b + (size_t)N * 64;       // N*64

    int nbN = (N + 255) / 256;
    int nbE = (E + 255) / 256;
    int NF4 = N * F / 4;

    // init
    hipMemsetAsync(cur, 0, (size_t)N * sizeof(int), stream);
    hipMemsetAsync(mm, 0xFF, 4, stream);   // min enc
    hipMemsetAsync(mm + 1, 0, 4, stream);  // max enc

    // CSR build (by dst)
    hist_kernel<<<nbE, 256, 0, stream>>>(dst, cur, E);
    scan_block<<<nbN, 256, 0, stream>>>(cur, off, bsum, N);
    scan_sums<<<1, 512, 0, stream>>>(bsum, nbN);
    scan_add<<<nbN, 256, 0, stream>>>(off, bsum, N);
    rdeg_cur<<<nbN, 256, 0, stream>>>(off, rdeg, cur, N, E);
    scatter_kernel<<<nbE, 256, 0, stream>>>(src, dst, cur, sE, E);

    // weights + input cast
    wprep<<<256, 256, 0, stream>>>(Ws1, Wn1, Ws2, Wn2, (ushort*)Wtb);
    cast_bf16<<<(NF4 + 255) / 256, 256, 0, stream>>>(x, xb, NF4);

    // layer 1
    agg_gather<<<(N + 3) / 4, 256, 0, stream>>>(xb, off, sE, rdeg, msgb, N, E);
    sage_mfma<<<(N + 63) / 64, 256, 0, stream>>>(xb, msgb, Wtb, b1, (ushort*)h1b, N);

    // layer 2
    agg_gather<<<(N + 3) / 4, 256, 0, stream>>>(h1b, off, sE, rdeg, msgb, N, E);
    sage_mfma<<<(N + 63) / 64, 256, 0, stream>>>(h1b, msgb, Wtb + 16384, b2, (ushort*)h2b, N);

    // edge scores (fused min/max) + normalize
    edge_score_csr<<<(N + 3) / 4, 256, 0, stream>>>(h2b, off, sE, out, mm, N, E);
    norm_kernel<<<(E + 255) / 256, 256, 0, stream>>>(out, mm, E);
}

// Round 7
// 750.958 us; speedup vs baseline: 1.6115x; 1.6115x over previous
//
#include <hip/hip_runtime.h>
#include <hip/hip_bf16.h>

#define F 128

typedef unsigned int uint;
typedef unsigned short ushort;
typedef __attribute__((ext_vector_type(8))) short short8;   // 8 bf16
typedef __attribute__((ext_vector_type(4))) float f32x4;

__device__ inline ushort f2bf(float f) {
    uint u = __float_as_uint(f);
    u += 0x7FFF + ((u >> 16) & 1);   // round-to-nearest-even
    return (ushort)(u >> 16);
}
__device__ inline float2 bf2f(uint u) {
    return make_float2(__uint_as_float(u << 16), __uint_as_float(u & 0xFFFF0000u));
}

// ---------------- CSR build ----------------
__global__ __launch_bounds__(256) void hist_kernel(const int* __restrict__ dst,
                                                   int* __restrict__ cnt, int E) {
    int e = blockIdx.x * 256 + threadIdx.x;
    if (e < E) atomicAdd(&cnt[dst[e]], 1);
}

__global__ __launch_bounds__(256) void scan_block(const int* __restrict__ cnt,
                                                  int* __restrict__ off,
                                                  int* __restrict__ bsum, int N) {
    __shared__ int t[256];
    int i = blockIdx.x * 256 + threadIdx.x;
    int v = (i < N) ? cnt[i] : 0;
    t[threadIdx.x] = v;
    __syncthreads();
    for (int o = 1; o < 256; o <<= 1) {
        int x = (threadIdx.x >= o) ? t[threadIdx.x - o] : 0;
        __syncthreads();
        t[threadIdx.x] += x;
        __syncthreads();
    }
    if (i < N) off[i] = t[threadIdx.x] - v;
    if (threadIdx.x == 255) bsum[blockIdx.x] = t[255];
}

__global__ __launch_bounds__(512) void scan_sums(int* __restrict__ bsum, int nb) {
    __shared__ int t[512];
    int v = (threadIdx.x < nb) ? bsum[threadIdx.x] : 0;
    t[threadIdx.x] = v;
    __syncthreads();
    for (int o = 1; o < 512; o <<= 1) {
        int x = (threadIdx.x >= o) ? t[threadIdx.x - o] : 0;
        __syncthreads();
        t[threadIdx.x] += x;
        __syncthreads();
    }
    if (threadIdx.x < nb) bsum[threadIdx.x] = t[threadIdx.x] - v;
}

__global__ __launch_bounds__(256) void scan_add(int* __restrict__ off,
                                                const int* __restrict__ bsum, int N) {
    int i = blockIdx.x * 256 + threadIdx.x;
    if (i < N) off[i] += bsum[blockIdx.x];
}

__global__ __launch_bounds__(256) void rdeg_cur(const int* __restrict__ off,
                                                float* __restrict__ rdeg,
                                                int* __restrict__ cur, int N, int E) {
    int i = blockIdx.x * 256 + threadIdx.x;
    if (i >= N) return;
    int b = off[i];
    int e = (i == N - 1) ? E : off[i + 1];
    rdeg[i] = 1.0f / fmaxf((float)(e - b), 1.0f);
    cur[i] = b;
}

__global__ __launch_bounds__(256) void scatter_kernel(const int* __restrict__ src,
                                                      const int* __restrict__ dst,
                                                      int* __restrict__ cur,
                                                      int2* __restrict__ sE, int E) {
    int e = blockIdx.x * 256 + threadIdx.x;
    if (e >= E) return;
    int d = dst[e];
    int p = atomicAdd(&cur[d], 1);
    sE[p] = make_int2(src[e], e);
}

// ---------------- weight prep: cast + transpose 4 matrices [k][n] -> bf16 [n][k] ----------------
__global__ __launch_bounds__(256) void wprep(const float* __restrict__ W0,
                                             const float* __restrict__ W1,
                                             const float* __restrict__ W2,
                                             const float* __restrict__ W3,
                                             ushort* __restrict__ Wt) {
    int idx = blockIdx.x * 256 + threadIdx.x;   // 4 * 128*128
    if (idx >= 4 * 16384) return;
    int mat = idx >> 14;
    int pos = idx & 16383;
    int k = pos >> 7, n = pos & 127;
    const float* W = (mat == 0) ? W0 : (mat == 1) ? W1 : (mat == 2) ? W2 : W3;
    Wt[mat * 16384 + n * 128 + k] = f2bf(W[k * 128 + n]);
}

// ---------------- f32 -> bf16 cast (x only) ----------------
__global__ __launch_bounds__(256) void cast_bf16(const float* __restrict__ in,
                                                 uint* __restrict__ outb, int n4) {
    int i = blockIdx.x * 256 + threadIdx.x;
    if (i >= n4) return;
    float4 v = ((const float4*)in)[i];
    uint ua = (uint)f2bf(v.x) | ((uint)f2bf(v.y) << 16);
    uint ub = (uint)f2bf(v.z) | ((uint)f2bf(v.w) << 16);
    ((uint2*)outb)[i] = make_uint2(ua, ub);
}

// ---------------- aggregate (gather): msg[n] = mean h[srcs] ----------------
// wave per node, lane per bf16x2; p wave-uniform -> coalesced row loads.
__global__ __launch_bounds__(256) void agg_gather(const uint* __restrict__ hb,
                                                  const int* __restrict__ off,
                                                  const int2* __restrict__ sE,
                                                  const float* __restrict__ rdeg,
                                                  uint* __restrict__ msgb, int N, int E) {
    int node = blockIdx.x * 4 + (threadIdx.x >> 6);
    int lane = threadIdx.x & 63;
    if (node >= N) return;
    int p = off[node];
    int pe = (node == N - 1) ? E : off[node + 1];
    float2 acc = make_float2(0.f, 0.f);
    for (; p + 3 < pe; p += 4) {
        int s0 = sE[p].x, s1 = sE[p + 1].x, s2 = sE[p + 2].x, s3 = sE[p + 3].x;
        float2 f0 = bf2f(hb[(size_t)s0 * 64 + lane]);
        float2 f1 = bf2f(hb[(size_t)s1 * 64 + lane]);
        float2 f2 = bf2f(hb[(size_t)s2 * 64 + lane]);
        float2 f3 = bf2f(hb[(size_t)s3 * 64 + lane]);
        acc.x += (f0.x + f1.x) + (f2.x + f3.x);
        acc.y += (f0.y + f1.y) + (f2.y + f3.y);
    }
    for (; p < pe; ++p) {
        float2 f = bf2f(hb[(size_t)sE[p].x * 64 + lane]);
        acc.x += f.x;
        acc.y += f.y;
    }
    float rd = rdeg[node];
    msgb[(size_t)node * 64 + lane] = (uint)f2bf(acc.x * rd) | ((uint)f2bf(acc.y * rd) << 16);
}

// ---------------- SAGE layer via MFMA ----------------
__global__ __launch_bounds__(256) void sage_mfma(const uint* __restrict__ hb,
                                                 const uint* __restrict__ mb,
                                                 const uint* __restrict__ Wt,
                                                 const float* __restrict__ bias,
                                                 ushort* __restrict__ outb, int N) {
    int wave = threadIdx.x >> 6, lane = threadIdx.x & 63;
    int m = lane & 15, q = lane >> 4;
    int r0 = blockIdx.x * 64 + wave * 16;
    int arow = r0 + m;
    if (arow >= N) arow = N - 1;

    f32x4 acc[8];
#pragma unroll
    for (int t = 0; t < 8; t++) acc[t] = (f32x4){0.f, 0.f, 0.f, 0.f};

    const uint* hrow = hb + (size_t)arow * 64;
    const uint* mrow = mb + (size_t)arow * 64;
#pragma unroll
    for (int sel = 0; sel < 2; sel++) {
        const uint* arowp = sel ? mrow : hrow;
        const uint* wsel = Wt + sel * 8192;
#pragma unroll
        for (int kk = 0; kk < 4; kk++) {
            int ko = kk * 16 + q * 4;
            short8 a = *(const short8*)(arowp + ko);
#pragma unroll
            for (int t = 0; t < 8; t++) {
                short8 b = *(const short8*)(wsel + (size_t)(16 * t + m) * 64 + ko);
                acc[t] = __builtin_amdgcn_mfma_f32_16x16x32_bf16(a, b, acc[t], 0, 0, 0);
            }
        }
    }

#pragma unroll
    for (int t = 0; t < 8; t++) {
        float bs = bias[16 * t + m];
#pragma unroll
        for (int r = 0; r < 4; r++) {
            int orow = r0 + q * 4 + r;
            if (orow < N) outb[(size_t)orow * 128 + 16 * t + m] = f2bf(acc[t][r] + bs);
        }
    }
}

// ---------------- edge score (no atomics, no min/max in this kernel) ----------------
__global__ __launch_bounds__(256) void edge_score_csr(const uint* __restrict__ hb,
                                                      const int* __restrict__ off,
                                                      const int2* __restrict__ sE,
                                                      float* __restrict__ s, int N, int E) {
    int node = blockIdx.x * 4 + (threadIdx.x >> 6);
    int lane = threadIdx.x & 63;
    if (node >= N) return;
    int p = off[node];
    int pe = (node == N - 1) ? E : off[node + 1];
    if (p >= pe) return;
    float2 d = bf2f(hb[(size_t)node * 64 + lane]);
    for (; p + 3 < pe; p += 4) {
        int2 se0 = sE[p], se1 = sE[p + 1], se2 = sE[p + 2], se3 = sE[p + 3];
        float2 a0 = bf2f(hb[(size_t)se0.x * 64 + lane]);
        float2 a1 = bf2f(hb[(size_t)se1.x * 64 + lane]);
        float2 a2 = bf2f(hb[(size_t)se2.x * 64 + lane]);
        float2 a3 = bf2f(hb[(size_t)se3.x * 64 + lane]);
        float v0 = a0.x * d.x + a0.y * d.y;
        float v1 = a1.x * d.x + a1.y * d.y;
        float v2 = a2.x * d.x + a2.y * d.y;
        float v3 = a3.x * d.x + a3.y * d.y;
#pragma unroll
        for (int o = 32; o > 0; o >>= 1) {
            v0 += __shfl_down(v0, o);
            v1 += __shfl_down(v1, o);
            v2 += __shfl_down(v2, o);
            v3 += __shfl_down(v3, o);
        }
        if (lane == 0) { s[se0.y] = v0; s[se1.y] = v1; s[se2.y] = v2; s[se3.y] = v3; }
    }
    for (; p < pe; ++p) {
        int2 se = sE[p];
        float2 a = bf2f(hb[(size_t)se.x * 64 + lane]);
        float v = a.x * d.x + a.y * d.y;
#pragma unroll
        for (int o = 32; o > 0; o >>= 1) v += __shfl_down(v, o);
        if (lane == 0) s[se.y] = v;
    }
}

// ---------------- two-stage atomic-free min/max ----------------
__global__ __launch_bounds__(256) void minmax_part(const float* __restrict__ s,
                                                   float2* __restrict__ pmm, int E) {
    float vmin = INFINITY, vmax = -INFINITY;
    for (int i = blockIdx.x * 256 + threadIdx.x; i < E; i += gridDim.x * 256) {
        float v = s[i];
        vmin = fminf(vmin, v);
        vmax = fmaxf(vmax, v);
    }
#pragma unroll
    for (int o = 1; o <= 32; o <<= 1) {
        vmin = fminf(vmin, __shfl_xor(vmin, o));
        vmax = fmaxf(vmax, __shfl_xor(vmax, o));
    }
    __shared__ float smin[4], smax[4];
    int lane = threadIdx.x & 63, wv = threadIdx.x >> 6;
    if (lane == 0) { smin[wv] = vmin; smax[wv] = vmax; }
    __syncthreads();
    if (threadIdx.x == 0) {
        float m = fminf(fminf(smin[0], smin[1]), fminf(smin[2], smin[3]));
        float M = fmaxf(fmaxf(smax[0], smax[1]), fmaxf(smax[2], smax[3]));
        pmm[blockIdx.x] = make_float2(m, M);
    }
}

__global__ __launch_bounds__(256) void minmax_final(const float2* __restrict__ pmm,
                                                    float* __restrict__ mmf, int nb) {
    float vmin = INFINITY, vmax = -INFINITY;
    for (int i = threadIdx.x; i < nb; i += 256) {
        float2 v = pmm[i];
        vmin = fminf(vmin, v.x);
        vmax = fmaxf(vmax, v.y);
    }
#pragma unroll
    for (int o = 1; o <= 32; o <<= 1) {
        vmin = fminf(vmin, __shfl_xor(vmin, o));
        vmax = fmaxf(vmax, __shfl_xor(vmax, o));
    }
    __shared__ float smin[4], smax[4];
    int lane = threadIdx.x & 63, wv = threadIdx.x >> 6;
    if (lane == 0) { smin[wv] = vmin; smax[wv] = vmax; }
    __syncthreads();
    if (threadIdx.x == 0) {
        mmf[0] = fminf(fminf(smin[0], smin[1]), fminf(smin[2], smin[3]));
        mmf[1] = fmaxf(fmaxf(smax[0], smax[1]), fmaxf(smax[2], smax[3]));
    }
}

__global__ __launch_bounds__(256) void norm_kernel(float* __restrict__ s,
                                                   const float* __restrict__ mmf, int E) {
    float mn = mmf[0];
    float mx = mmf[1];
    float inv = 1.0f / (mx - mn);
    int i = blockIdx.x * 256 + threadIdx.x;
    if (i < E) s[i] = (s[i] - mn) * inv;
}

extern "C" void kernel_launch(void* const* d_in, const int* in_sizes, int n_in,
                              void* d_out, int out_size, void* d_ws, size_t ws_size,
                              hipStream_t stream) {
    const float* x   = (const float*)d_in[0];
    const int*   src = (const int*)d_in[1];
    const int*   dst = (const int*)d_in[2];
    const float* Ws1 = (const float*)d_in[3];
    const float* Wn1 = (const float*)d_in[4];
    const float* b1  = (const float*)d_in[5];
    const float* Ws2 = (const float*)d_in[6];
    const float* Wn2 = (const float*)d_in[7];
    const float* b2  = (const float*)d_in[8];

    int N = in_sizes[0] / F;   // 100000
    int E = in_sizes[1];       // 1600000
    float* out = (float*)d_out;

    // workspace layout (4-byte elements)
    int* off  = (int*)d_ws;                  // N
    int* cur  = off + N;                     // N
    int2* sE  = (int2*)(cur + N);            // E int2 (2E words)
    int* bsum = (int*)(sE + E);              // 1024
    float* rdeg = (float*)(bsum + 1024);     // N
    float* mmf = (float*)(rdeg + N);         // 2 (+2 pad)
    float2* pmm = (float2*)(mmf + 4);        // 1024 float2 (2048 words)
    uint* Wtb = (uint*)(pmm + 1024);         // 4*16384 bf16 = 32768 uints
    size_t elemOff = 3 * (size_t)N + 2 * (size_t)E + 1024 + 4 + 2048 + 32768;
    elemOff = (elemOff + 3) & ~(size_t)3;    // 16B align
    uint* xb   = (uint*)d_ws + elemOff;      // N*64
    uint* msgb = xb + (size_t)N * 64;        // N*64
    uint* h1b  = msgb + (size_t)N * 64;      // N*64
    uint* h2b  = h1b + (size_t)N * 64;       // N*64

    int nbN = (N + 255) / 256;
    int nbE = (E + 255) / 256;
    int NF4 = N * F / 4;

    // init
    hipMemsetAsync(cur, 0, (size_t)N * sizeof(int), stream);

    // CSR build (by dst)
    hist_kernel<<<nbE, 256, 0, stream>>>(dst, cur, E);
    scan_block<<<nbN, 256, 0, stream>>>(cur, off, bsum, N);
    scan_sums<<<1, 512, 0, stream>>>(bsum, nbN);
    scan_add<<<nbN, 256, 0, stream>>>(off, bsum, N);
    rdeg_cur<<<nbN, 256, 0, stream>>>(off, rdeg, cur, N, E);
    scatter_kernel<<<nbE, 256, 0, stream>>>(src, dst, cur, sE, E);

    // weights + input cast
    wprep<<<256, 256, 0, stream>>>(Ws1, Wn1, Ws2, Wn2, (ushort*)Wtb);
    cast_bf16<<<(NF4 + 255) / 256, 256, 0, stream>>>(x, xb, NF4);

    // layer 1
    agg_gather<<<(N + 3) / 4, 256, 0, stream>>>(xb, off, sE, rdeg, msgb, N, E);
    sage_mfma<<<(N + 63) / 64, 256, 0, stream>>>(xb, msgb, Wtb, b1, (ushort*)h1b, N);

    // layer 2
    agg_gather<<<(N + 3) / 4, 256, 0, stream>>>(h1b, off, sE, rdeg, msgb, N, E);
    sage_mfma<<<(N + 63) / 64, 256, 0, stream>>>(h1b, msgb, Wtb + 16384, b2, (ushort*)h2b, N);

    // edge scores + two-stage min/max + normalize
    edge_score_csr<<<(N + 3) / 4, 256, 0, stream>>>(h2b, off, sE, out, N, E);
    minmax_part<<<1024, 256, 0, stream>>>(out, pmm, E);
    minmax_final<<<1, 256, 0, stream>>>(pmm, mmf, 1024);
    norm_kernel<<<(E + 255) / 256, 256, 0, stream>>>(out, mmf, E);
}